// Round 11
// baseline (2367.342 us; speedup 1.0000x reference)
//
#include <hip/hip_runtime.h>

// RecNet: 100-step recurrent LIF SNN + LI readout. Exact fp64 trajectory.
// R11: i8 exact-slice GEMM (validated R10) with two fixes:
//   (1) XCD-affine block map: 8 n-blocks of an m-tile -> same XCD -> A-slab
//       fetched once per XCD L2 (was 8x HBM re-fetch, FETCH 1.9GB).
//   (2) staging loads for kt+1 issued BEFORE the mfma phase of kt (latency
//       hidden under ~3100cy of MFMA); launch_bounds(256,1) -> 512 VGPR cap.
//   lif : persistent, one block per batch element, spike-sparse gather.

#define TT    100
#define BATCH 512
#define FDIM  784
#define HDIM  512
#define ODIM  10
#define NSTATE (BATCH * HDIM)
#define KPAD  832          // 13 * 64

#define DTM 0.1
#define DTS 0.2

typedef int i32x4 __attribute__((ext_vector_type(4)));

// Layout-hypothesis decoder shared by probe and gemm (consistent by construction).
__device__ __forceinline__ void h_maps(int H, int lane,
                                       int& am, int& ak, int& bn, int& bk,
                                       int dr[4], int dc[4]) {
  const int l15 = lane & 15, l4 = lane >> 4;
  const int lq = lane >> 2, l3 = lane & 3;
  if (H & 1) { am = lq;  ak = l3; } else { am = l15; ak = l4; }
  if (H & 2) { bn = lq;  bk = l3; } else { bn = l15; bk = l4; }
  const int dmode = H >> 2;
#pragma unroll
  for (int r = 0; r < 4; ++r) {
    const int rr = (dmode & 1) ? (l4 + (r << 2)) : ((l4 << 2) + r);
    if (dmode & 2) { dr[r] = l15; dc[r] = rr; }
    else           { dr[r] = rr;  dc[r] = l15; }
  }
}

__device__ __forceinline__ int af_val(int m, int k, int s) {
  return ((3 * m + 5 * k + 7 * s) % 11) - 5;
}
__device__ __forceinline__ int bf_val(int n, int k, int s) {
  return ((2 * n + 7 * k + 3 * s) % 13) - 6;
}

// ---------------- probe: find the true i8 16x16x64 MFMA layout ----------------
__global__ __launch_bounds__(64) void probe_kernel(int* __restrict__ flag) {
  const int lane = threadIdx.x;
  int winner = -1;
  for (int Hh = 0; Hh < 16; ++Hh) {
    int am, ak, bn, bk, dr[4], dc[4];
    h_maps(Hh, lane, am, ak, bn, bk, dr, dc);
    bool ok = true;
    for (int s = 0; s < 2; ++s) {
      union { signed char c[16]; i32x4 v; } ua, ub;
#pragma unroll
      for (int j = 0; j < 16; ++j) {
        ua.c[j] = (signed char)af_val(am, (ak << 4) + j, s);
        ub.c[j] = (signed char)bf_val(bn, (bk << 4) + j, s);
      }
      i32x4 d = {0, 0, 0, 0};
      d = __builtin_amdgcn_mfma_i32_16x16x64_i8(ua.v, ub.v, d, 0, 0, 0);
#pragma unroll
      for (int r = 0; r < 4; ++r) {
        int ref = 0;
        for (int k = 0; k < 64; ++k) ref += af_val(dr[r], k, s) * bf_val(dc[r], k, s);
        ok = ok && (d[r] == ref);
      }
    }
    if (__all(ok) && winner < 0) winner = Hh;
  }
  if (lane == 0) *flag = winner;
}

// ---------------- exact 5-digit slicing: one wave per row ----------------
__global__ __launch_bounds__(256) void slice_kernel(const float* __restrict__ src,
                                                    int rows,
                                                    signed char* __restrict__ dst,
                                                    int* __restrict__ Edst) {
  const int w = (blockIdx.x << 2) + (threadIdx.x >> 6);
  if (w >= rows) return;
  const int lane = threadIdx.x & 63;
  const float* rowp = src + (size_t)w * FDIM;
  float vals[13];
  float mx = 0.0f;
#pragma unroll
  for (int j = 0; j < 13; ++j) {
    const int k = lane + (j << 6);
    const float v = (k < FDIM) ? rowp[k] : 0.0f;
    vals[j] = v;
    mx = fmaxf(mx, fabsf(v));
  }
#pragma unroll
  for (int o = 32; o; o >>= 1) mx = fmaxf(mx, __shfl_xor(mx, o));
  const int E = (mx > 0.0f) ? (ilogbf(mx) + 3) : 3;
  if (lane == 0) Edst[w] = E;
#pragma unroll
  for (int j = 0; j < 13; ++j) {
    const int k = lane + (j << 6);
    long long I = (long long)ldexp((double)vals[j], 40 - E);   // |I| < 2^38, exact
#pragma unroll
    for (int s = 0; s < 5; ++s) {
      int b = (int)(I & 255);
      if (b > 127) { b -= 256; I += 256; }
      I >>= 8;
      dst[(size_t)s * rows * KPAD + (size_t)w * KPAD + k] = (signed char)b;
    }
  }
}

// ---------------- K1: C[m][n] = sum_k A[m][k]*B[n][k] ----------------
// i8 path: block 128m x 64n, 4 waves (2 qm x 2 qn), wave 64m x 32n = 4x2 frags.
// 19 digit-pairs (g=sa+sb>=3) -> 6 shared i32 accumulator groups.
// XCD-affine id decode + load-ahead staging pipeline.
__global__ __launch_bounds__(256, 1) void gemm_in_kernel(
    const float* __restrict__ A, const float* __restrict__ B,
    const signed char* __restrict__ aslc, const signed char* __restrict__ bslc,
    const int* __restrict__ Ea, const int* __restrict__ Eb,
    double* __restrict__ C, const int* __restrict__ flag) {
  __shared__ __align__(16) char smem[76800];
  const int tid = threadIdx.x;
  // XCD-affine decode: hw round-robins blockIdx%8 across XCDs. Blocks with the
  // same (id&7) run on one XCD in j-order; n varies fastest within an m-tile,
  // so its 8 n-blocks are temporally adjacent on that XCD -> A-slab L2 reuse.
  const int id  = blockIdx.x;
  const int xcd = id & 7;
  const int j   = id >> 3;                    // 0..399 per XCD
  const int Mt  = xcd * 50 + (j >> 3);        // 0..399
  const int Nt  = j & 7;                      // 0..7
  const int m0 = Mt << 7;
  const int n0 = Nt << 6;
  const int H = flag[0];

  if (H >= 0) {
    // ---------- i8 exact-slice path ----------
    const int lane = tid & 63;
    const int qm = (tid >> 6) & 1;
    const int qn = tid >> 7;
    int am, ak, bn, bk, dr[4], dc[4];
    h_maps(H, lane, am, ak, bn, bk, dr, dc);
    signed char* Ab = (signed char*)smem;            // [5][128][80]
    signed char* Bb = (signed char*)smem + 51200;    // [5][64][80]

    i32x4 acc[6][4][2];
#pragma unroll
    for (int gi = 0; gi < 6; ++gi)
#pragma unroll
      for (int mf = 0; mf < 4; ++mf)
#pragma unroll
        for (int nf = 0; nf < 2; ++nf) acc[gi][mf][nf] = (i32x4){0, 0, 0, 0};

    // per-slot staging decode (slot c = tid + it*256)
    const signed char* gsrcA[15];
    char* ldst_[15];
#pragma unroll
    for (int it = 0; it < 15; ++it) {
      const int c = tid + (it << 8);
      if (c < 2560) {
        const int sa = c >> 9, rem = c & 511, row = rem >> 2, q = rem & 3;
        gsrcA[it] = aslc + (size_t)sa * (51200ull * KPAD)
                    + (size_t)(m0 + row) * KPAD + (q << 4);
        ldst_[it] = (char*)(Ab + sa * 10240 + row * 80 + (q << 4));
      } else {
        const int c2 = c - 2560;
        const int sb = c2 >> 8, rem = c2 & 255, row = rem >> 2, q = rem & 3;
        gsrcA[it] = bslc + (size_t)sb * (512ull * KPAD)
                    + (size_t)(n0 + row) * KPAD + (q << 4);
        ldst_[it] = (char*)(Bb + sb * 5120 + row * 80 + (q << 4));
      }
    }

    int4 stg[15];
#pragma unroll
    for (int it = 0; it < 15; ++it)
      stg[it] = *(const int4*)(gsrcA[it]);           // kt = 0

    for (int kt = 0; kt < 13; ++kt) {
      __syncthreads();                               // prev mfma done reading
#pragma unroll
      for (int it = 0; it < 15; ++it) *(int4*)ldst_[it] = stg[it];
      __syncthreads();                               // tile ready
      if (kt < 12) {
#pragma unroll
        for (int it = 0; it < 15; ++it)
          stg[it] = *(const int4*)(gsrcA[it] + (kt + 1) * 64);  // in flight under mfma
      }

      i32x4 af[4][5], bf[2][5];
#pragma unroll
      for (int mf = 0; mf < 4; ++mf)
#pragma unroll
        for (int sa = 0; sa < 5; ++sa)
          af[mf][sa] = *(const i32x4*)(Ab + sa * 10240
                          + ((qm << 6) + (mf << 4) + am) * 80 + (ak << 4));
#pragma unroll
      for (int nf = 0; nf < 2; ++nf)
#pragma unroll
        for (int sb = 0; sb < 5; ++sb)
          bf[nf][sb] = *(const i32x4*)(Bb + sb * 5120
                          + ((qn << 5) + (nf << 4) + bn) * 80 + (bk << 4));
#pragma unroll
      for (int sa = 0; sa < 5; ++sa)
#pragma unroll
        for (int sb = 0; sb < 5; ++sb) {
          if (sa + sb < 3) continue;                 // tails ~1e-10, dropped
          const int gi = sa + sb - 3;
#pragma unroll
          for (int mf = 0; mf < 4; ++mf)
#pragma unroll
            for (int nf = 0; nf < 2; ++nf)
              acc[gi][mf][nf] = __builtin_amdgcn_mfma_i32_16x16x64_i8(
                  af[mf][sa], bf[nf][sb], acc[gi][mf][nf], 0, 0, 0);
        }
    }

    // epilogue: out = sum_g acc_g * 2^(Ea+Eb-80+8g), exact pow2 scales
#pragma unroll
    for (int mf = 0; mf < 4; ++mf)
#pragma unroll
      for (int nf = 0; nf < 2; ++nf)
#pragma unroll
        for (int r = 0; r < 4; ++r) {
          const int row = m0 + (qm << 6) + (mf << 4) + dr[r];
          const int col = n0 + (qn << 5) + (nf << 4) + dc[r];
          const int e0 = Ea[row] + Eb[col] - 80;
          double s = 0.0;
#pragma unroll
          for (int g = 8; g >= 3; --g) {
            const long long bits = ((long long)(e0 + 8 * g + 1023)) << 52;
            s += (double)acc[g - 3][mf][nf][r] * __longlong_as_double(bits);
          }
          C[(size_t)row * HDIM + col] = s;
        }
  } else {
    // ---------- fp64 VALU fallback (r9-verified): 128m x 64n, 8x4 micro ----------
    double (*As)[130] = (double(*)[130])smem;                  // [16][130]
    double (*Bs)[66]  = (double(*)[66])(smem + 16640);         // [16][66]
    const int tn = tid & 15;
    const int tm = tid >> 4;
    double acc[8][4] = {};
    for (int kt = 0; kt < 49; ++kt) {
      __syncthreads();
#pragma unroll
      for (int s = 0; s < 2; ++s) {
        const int idx = tid + (s << 8);
        const int row = idx >> 2;
        const int kc  = (idx & 3) << 2;
        const float4 a = *(const float4*)(A + (size_t)(m0 + row) * FDIM + kt * 16 + kc);
        As[kc + 0][row] = (double)a.x; As[kc + 1][row] = (double)a.y;
        As[kc + 2][row] = (double)a.z; As[kc + 3][row] = (double)a.w;
      }
      {
        const int row = tid >> 2;
        const int kc  = (tid & 3) << 2;
        const float4 b = *(const float4*)(B + (size_t)(n0 + row) * FDIM + kt * 16 + kc);
        Bs[kc + 0][row] = (double)b.x; Bs[kc + 1][row] = (double)b.y;
        Bs[kc + 2][row] = (double)b.z; Bs[kc + 3][row] = (double)b.w;
      }
      __syncthreads();
#pragma unroll
      for (int kk = 0; kk < 16; ++kk) {
        double av[8], bv[4];
        *(double2*)&av[0] = *(const double2*)&As[kk][(tm << 3) + 0];
        *(double2*)&av[2] = *(const double2*)&As[kk][(tm << 3) + 2];
        *(double2*)&av[4] = *(const double2*)&As[kk][(tm << 3) + 4];
        *(double2*)&av[6] = *(const double2*)&As[kk][(tm << 3) + 6];
        *(double2*)&bv[0] = *(const double2*)&Bs[kk][(tn << 2) + 0];
        *(double2*)&bv[2] = *(const double2*)&Bs[kk][(tn << 2) + 2];
#pragma unroll
        for (int i = 0; i < 8; ++i)
#pragma unroll
          for (int j2 = 0; j2 < 4; ++j2) acc[i][j2] += av[i] * bv[j2];
      }
    }
#pragma unroll
    for (int i = 0; i < 8; ++i) {
      double* crow = C + (size_t)(m0 + (tm << 3) + i) * HDIM + n0 + (tn << 2);
      *(double2*)(crow)     = make_double2(acc[i][0], acc[i][1]);
      *(double2*)(crow + 2) = make_double2(acc[i][2], acc[i][3]);
    }
  }
}

// ---------------- transpose w_rec [512][512] -> wrt [k][h] ----------------
__global__ __launch_bounds__(256) void transpose_kernel(const float* __restrict__ src,
                                                        float* __restrict__ dst) {
  __shared__ float tile[32][33];
  const int bx = blockIdx.x & 15, by = blockIdx.x >> 4;
  const int tx = threadIdx.x & 31, ty = threadIdx.x >> 5;
  const int x = (bx << 5) + tx;
#pragma unroll
  for (int s = 0; s < 32; s += 8)
    tile[ty + s][tx] = src[(size_t)((by << 5) + ty + s) * HDIM + x];
  __syncthreads();
  const int xo = (by << 5) + tx;
#pragma unroll
  for (int s = 0; s < 32; s += 8)
    dst[(size_t)((bx << 5) + ty + s) * HDIM + xo] = tile[tx][ty + s];
}

// ---------------- w_out [10][512] -> wot [k][16] ----------------
__global__ __launch_bounds__(256) void wot_kernel(const float* __restrict__ w_out,
                                                  float* __restrict__ wot) {
  const int k = (blockIdx.x << 8) + threadIdx.x;
#pragma unroll
  for (int o = 0; o < ODIM; ++o) wot[(k << 4) + o] = w_out[(size_t)o * HDIM + k];
}

// ---------------- K2: persistent LIF+LI, one block per batch element ----------
__global__ __launch_bounds__(256) void lif_kernel(const double* __restrict__ cin,
                                                  const float* __restrict__ wrt,
                                                  const float* __restrict__ wot,
                                                  float* __restrict__ out) {
  const int b = blockIdx.x;
  const int tid = threadIdx.x;
  const int h0 = tid, h1 = tid + 256;

  __shared__ unsigned long long masks[8];
  __shared__ int offs[9];
  __shared__ __align__(8) unsigned short list[528];
  __shared__ double ypart[256];

  if (tid == 0) offs[8] = 0;
  __syncthreads();

  double v0 = 0.0, v1 = 0.0, i0 = 0.0, i1 = 0.0;
  double lv = 0.0, li = 0.0;

  const double* cinb = cin + (size_t)b * HDIM;
  float* outb = out + (size_t)b * ODIM;

  for (int t = 0; t < TT; ++t) {
    const double vd0 = v0 + DTM * ((0.0 - v0) + i0);
    const double vd1 = v1 + DTM * ((0.0 - v1) + i1);
    const bool s0 = (vd0 - 1.0) > 0.0;
    const bool s1 = (vd1 - 1.0) > 0.0;
    v0 = s0 ? 0.0 : vd0;
    v1 = s1 ? 0.0 : vd1;
    i0 = i0 - DTS * i0;
    i1 = i1 - DTS * i1;

    const double c0 = cinb[(size_t)t * NSTATE + h0];
    const double c1 = cinb[(size_t)t * NSTATE + h1];

    {
      const int nf = offs[8];
      const int nfp = (nf + 3) & ~3;
      if (nfp > 0) {
        float A0[4], A1[4], B0[4] = {}, B1[4] = {};
#define LOADG(base, X0, X1)                                                   \
        do {                                                                  \
          const unsigned long long le = *(const unsigned long long*)&list[base]; \
          const int k0 = (int)(le & 0xffffu), k1 = (int)((le >> 16) & 0xffffu); \
          const int k2 = (int)((le >> 32) & 0xffffu), k3 = (int)(le >> 48);   \
          X0[0] = wrt[(k0 << 9) + h0]; X1[0] = wrt[(k0 << 9) + h1];           \
          X0[1] = wrt[(k1 << 9) + h0]; X1[1] = wrt[(k1 << 9) + h1];           \
          X0[2] = wrt[(k2 << 9) + h0]; X1[2] = wrt[(k2 << 9) + h1];           \
          X0[3] = wrt[(k3 << 9) + h0]; X1[3] = wrt[(k3 << 9) + h1];           \
        } while (0)
        LOADG(0, A0, A1);
        for (int g = 0; g < nfp; g += 4) {
          if (g + 4 < nfp) LOADG(g + 4, B0, B1);
          i0 += (double)A0[0]; i1 += (double)A1[0];
          i0 += (double)A0[1]; i1 += (double)A1[1];
          i0 += (double)A0[2]; i1 += (double)A1[2];
          i0 += (double)A0[3]; i1 += (double)A1[3];
#pragma unroll
          for (int j = 0; j < 4; ++j) { A0[j] = B0[j]; A1[j] = B1[j]; }
        }
#undef LOADG
      }
    }
    i0 += c0;
    i1 += c1;

    __syncthreads();  // B1

    {
      const unsigned long long m0 = __ballot(s0);
      const unsigned long long m1 = __ballot(s1);
      const int w = tid >> 6;
      if ((tid & 63) == 0) { masks[w] = m0; masks[4 + w] = m1; }
    }
    __syncthreads();  // B2
    if (tid == 0) {
      int rr = 0;
#pragma unroll
      for (int q = 0; q < 8; ++q) { offs[q] = rr; rr += __popcll(masks[q]); }
      offs[8] = rr;
    }
    __syncthreads();  // B3
    if (tid < 8) {
      unsigned long long m = masks[tid];
      int o = offs[tid];
      const int base = tid << 6;
      while (m) {
        list[o++] = (unsigned short)(base + __builtin_ctzll(m));
        m &= m - 1;
      }
    }
    if (tid < 4) list[offs[8] + tid] = 512;
    __syncthreads();  // B4

    {
      const int o = tid & 15, q = tid >> 4;
      const int nfc = offs[8];
      double yp = 0.0;
      int kk = q;
      if (kk < nfc) {
        float f = wot[((int)list[kk] << 4) + o];
        for (kk += 16; kk < nfc; kk += 16) {
          const float fn = wot[((int)list[kk] << 4) + o];
          yp += (double)f;
          f = fn;
        }
        yp += (double)f;
      }
      ypart[(o << 4) + q] = yp;
    }
    __syncthreads();  // B5
    if (tid < ODIM) {
      double y = 0.0;
      const double* yr = &ypart[tid << 4];
#pragma unroll
      for (int q = 0; q < 16; ++q) y += yr[q];
      const double lvn = lv + DTM * ((0.0 - lv) + li);
      li = (li - DTS * li) + y;
      lv = lvn;
      outb[(size_t)t * (BATCH * ODIM) + tid] = (float)lvn;
    }
  }
}

extern "C" void kernel_launch(void* const* d_in, const int* in_sizes, int n_in,
                              void* d_out, int out_size, void* d_ws, size_t ws_size,
                              hipStream_t stream) {
  const float* x     = (const float*)d_in[0];   // [100,512,784]
  const float* w_in  = (const float*)d_in[1];   // [512,784]
  const float* w_rec = (const float*)d_in[2];   // [512,512]
  const float* w_out = (const float*)d_in[3];   // [10,512]
  float* out = (float*)d_out;                   // [100,512,10] fp32

  const size_t CIN = (size_t)TT * BATCH * HDIM;         // 26,214,400 doubles
  double* cin = (double*)d_ws;
  float* wrt  = (float*)(cin + CIN);                    // [513][512], row 512 zeros
  float* wot  = wrt + 513 * 512;                        // [513][16]
  int*   flags = (int*)(wot + 513 * 16);                // 4 ints
  signed char* xslc = (signed char*)(flags + 4);        // [5][51200][832]
  signed char* wslc = xslc + 5ull * 51200 * KPAD;       // [5][512][832]
  int* Ea = (int*)(wslc + 5ull * 512 * KPAD);           // [51200]
  int* Eb = Ea + 51200;                                 // [512]

  const size_t zero_bytes = (513ull * 512 + 513ull * 16) * sizeof(float);
  const size_t need_min = CIN * sizeof(double) + zero_bytes + 16;
  const size_t need_i8  = need_min + 5ull * 51200 * KPAD + 5ull * 512 * KPAD
                        + (51200ull + 512) * sizeof(int);
  if (ws_size < need_min) {
    hipMemsetAsync(d_out, 0x7F, (size_t)out_size * sizeof(float), stream);
    return;
  }
  const bool use_i8 = (ws_size >= need_i8);

  hipMemsetAsync(wrt, 0, zero_bytes, stream);
  if (use_i8) {
    probe_kernel<<<1, 64, 0, stream>>>(flags);
    slice_kernel<<<12800, 256, 0, stream>>>(x, 51200, xslc, Ea);
    slice_kernel<<<128, 256, 0, stream>>>(w_in, 512, wslc, Eb);
  } else {
    hipMemsetAsync(flags, 0xFF, 4, stream);   // flag = -1 -> fp64 fallback path
  }
  transpose_kernel<<<256, 256, 0, stream>>>(w_rec, wrt);
  wot_kernel<<<2, 256, 0, stream>>>(w_out, wot);
  gemm_in_kernel<<<3200, 256, 0, stream>>>(x, w_in, xslc, wslc, Ea, Eb,
                                           cin, flags);
  lif_kernel<<<BATCH, 256, 0, stream>>>(cin, wrt, wot, out);
}

// Round 12
// 1342.692 us; speedup vs baseline: 1.7631x; 1.7631x over previous
//
#include <hip/hip_runtime.h>

// RecNet: 100-step recurrent LIF SNN + LI readout. Exact fp64 trajectory.
// R12: i8 exact-slice GEMM. XCD-affine block map (R11, FETCH 1.9GB->320MB) +
//      R10's short-lived staging loop (R11's register prefetch spilled to
//      scratch: WRITE 2.27GB). No long-lived staging registers.
//   lif : persistent, one block per batch element, spike-sparse gather.

#define TT    100
#define BATCH 512
#define FDIM  784
#define HDIM  512
#define ODIM  10
#define NSTATE (BATCH * HDIM)
#define KPAD  832          // 13 * 64

#define DTM 0.1
#define DTS 0.2

typedef int i32x4 __attribute__((ext_vector_type(4)));

// Layout-hypothesis decoder shared by probe and gemm (consistent by construction).
__device__ __forceinline__ void h_maps(int H, int lane,
                                       int& am, int& ak, int& bn, int& bk,
                                       int dr[4], int dc[4]) {
  const int l15 = lane & 15, l4 = lane >> 4;
  const int lq = lane >> 2, l3 = lane & 3;
  if (H & 1) { am = lq;  ak = l3; } else { am = l15; ak = l4; }
  if (H & 2) { bn = lq;  bk = l3; } else { bn = l15; bk = l4; }
  const int dmode = H >> 2;
#pragma unroll
  for (int r = 0; r < 4; ++r) {
    const int rr = (dmode & 1) ? (l4 + (r << 2)) : ((l4 << 2) + r);
    if (dmode & 2) { dr[r] = l15; dc[r] = rr; }
    else           { dr[r] = rr;  dc[r] = l15; }
  }
}

__device__ __forceinline__ int af_val(int m, int k, int s) {
  return ((3 * m + 5 * k + 7 * s) % 11) - 5;
}
__device__ __forceinline__ int bf_val(int n, int k, int s) {
  return ((2 * n + 7 * k + 3 * s) % 13) - 6;
}

// ---------------- probe: find the true i8 16x16x64 MFMA layout ----------------
__global__ __launch_bounds__(64) void probe_kernel(int* __restrict__ flag) {
  const int lane = threadIdx.x;
  int winner = -1;
  for (int Hh = 0; Hh < 16; ++Hh) {
    int am, ak, bn, bk, dr[4], dc[4];
    h_maps(Hh, lane, am, ak, bn, bk, dr, dc);
    bool ok = true;
    for (int s = 0; s < 2; ++s) {
      union { signed char c[16]; i32x4 v; } ua, ub;
#pragma unroll
      for (int j = 0; j < 16; ++j) {
        ua.c[j] = (signed char)af_val(am, (ak << 4) + j, s);
        ub.c[j] = (signed char)bf_val(bn, (bk << 4) + j, s);
      }
      i32x4 d = {0, 0, 0, 0};
      d = __builtin_amdgcn_mfma_i32_16x16x64_i8(ua.v, ub.v, d, 0, 0, 0);
#pragma unroll
      for (int r = 0; r < 4; ++r) {
        int ref = 0;
        for (int k = 0; k < 64; ++k) ref += af_val(dr[r], k, s) * bf_val(dc[r], k, s);
        ok = ok && (d[r] == ref);
      }
    }
    if (__all(ok) && winner < 0) winner = Hh;
  }
  if (lane == 0) *flag = winner;
}

// ---------------- exact 5-digit slicing: one wave per row ----------------
__global__ __launch_bounds__(256) void slice_kernel(const float* __restrict__ src,
                                                    int rows,
                                                    signed char* __restrict__ dst,
                                                    int* __restrict__ Edst) {
  const int w = (blockIdx.x << 2) + (threadIdx.x >> 6);
  if (w >= rows) return;
  const int lane = threadIdx.x & 63;
  const float* rowp = src + (size_t)w * FDIM;
  float vals[13];
  float mx = 0.0f;
#pragma unroll
  for (int j = 0; j < 13; ++j) {
    const int k = lane + (j << 6);
    const float v = (k < FDIM) ? rowp[k] : 0.0f;
    vals[j] = v;
    mx = fmaxf(mx, fabsf(v));
  }
#pragma unroll
  for (int o = 32; o; o >>= 1) mx = fmaxf(mx, __shfl_xor(mx, o));
  const int E = (mx > 0.0f) ? (ilogbf(mx) + 3) : 3;
  if (lane == 0) Edst[w] = E;
#pragma unroll
  for (int j = 0; j < 13; ++j) {
    const int k = lane + (j << 6);
    long long I = (long long)ldexp((double)vals[j], 40 - E);   // |I| < 2^38, exact
#pragma unroll
    for (int s = 0; s < 5; ++s) {
      int b = (int)(I & 255);
      if (b > 127) { b -= 256; I += 256; }
      I >>= 8;
      dst[(size_t)s * rows * KPAD + (size_t)w * KPAD + k] = (signed char)b;
    }
  }
}

// ---------------- K1: C[m][n] = sum_k A[m][k]*B[n][k] ----------------
// i8 path: block 128m x 64n, 4 waves (2 qm x 2 qn), wave 64m x 32n = 4x2 frags.
// 19 digit-pairs (g=sa+sb>=3) -> 6 shared i32 accumulator groups.
// XCD-affine id decode; staging = short-lived load->LDS (no spills).
__global__ __launch_bounds__(256, 1) void gemm_in_kernel(
    const float* __restrict__ A, const float* __restrict__ B,
    const signed char* __restrict__ aslc, const signed char* __restrict__ bslc,
    const int* __restrict__ Ea, const int* __restrict__ Eb,
    double* __restrict__ C, const int* __restrict__ flag) {
  __shared__ __align__(16) char smem[76800];
  const int tid = threadIdx.x;
  // XCD-affine decode: blocks with same (id&7) land on one XCD in j-order;
  // n varies fastest -> 8 n-blocks of an m-tile temporally adjacent per XCD.
  const int id  = blockIdx.x;
  const int xcd = id & 7;
  const int j   = id >> 3;                    // 0..399 per XCD
  const int Mt  = xcd * 50 + (j >> 3);        // 0..399
  const int Nt  = j & 7;                      // 0..7
  const int m0 = Mt << 7;
  const int n0 = Nt << 6;
  const int H = flag[0];

  if (H >= 0) {
    // ---------- i8 exact-slice path ----------
    const int lane = tid & 63;
    const int qm = (tid >> 6) & 1;
    const int qn = tid >> 7;
    int am, ak, bn, bk, dr[4], dc[4];
    h_maps(H, lane, am, ak, bn, bk, dr, dc);
    signed char* Ab = (signed char*)smem;            // [5][128][80]
    signed char* Bb = (signed char*)smem + 51200;    // [5][64][80]

    i32x4 acc[6][4][2];
#pragma unroll
    for (int gi = 0; gi < 6; ++gi)
#pragma unroll
      for (int mf = 0; mf < 4; ++mf)
#pragma unroll
        for (int nf = 0; nf < 2; ++nf) acc[gi][mf][nf] = (i32x4){0, 0, 0, 0};

    for (int kt = 0; kt < 13; ++kt) {
      __syncthreads();
#pragma unroll
      for (int it = 0; it < 15; ++it) {
        const int c = tid + (it << 8);
        const int4* gsrc;
        char* ldst;
        if (c < 2560) {
          const int sa = c >> 9, rem = c & 511, row = rem >> 2, q = rem & 3;
          gsrc = (const int4*)(aslc + (size_t)sa * (51200ull * KPAD)
                               + (size_t)(m0 + row) * KPAD + kt * 64 + (q << 4));
          ldst = (char*)(Ab + sa * 10240 + row * 80 + (q << 4));
        } else {
          const int c2 = c - 2560;
          const int sb = c2 >> 8, rem = c2 & 255, row = rem >> 2, q = rem & 3;
          gsrc = (const int4*)(bslc + (size_t)sb * (512ull * KPAD)
                               + (size_t)(n0 + row) * KPAD + kt * 64 + (q << 4));
          ldst = (char*)(Bb + sb * 5120 + row * 80 + (q << 4));
        }
        *(int4*)ldst = *gsrc;
      }
      __syncthreads();

      i32x4 af[4][5], bf[2][5];
#pragma unroll
      for (int mf = 0; mf < 4; ++mf)
#pragma unroll
        for (int sa = 0; sa < 5; ++sa)
          af[mf][sa] = *(const i32x4*)(Ab + sa * 10240
                          + ((qm << 6) + (mf << 4) + am) * 80 + (ak << 4));
#pragma unroll
      for (int nf = 0; nf < 2; ++nf)
#pragma unroll
        for (int sb = 0; sb < 5; ++sb)
          bf[nf][sb] = *(const i32x4*)(Bb + sb * 5120
                          + ((qn << 5) + (nf << 4) + bn) * 80 + (bk << 4));
#pragma unroll
      for (int sa = 0; sa < 5; ++sa)
#pragma unroll
        for (int sb = 0; sb < 5; ++sb) {
          if (sa + sb < 3) continue;                 // tails ~1e-10, dropped
          const int gi = sa + sb - 3;
#pragma unroll
          for (int mf = 0; mf < 4; ++mf)
#pragma unroll
            for (int nf = 0; nf < 2; ++nf)
              acc[gi][mf][nf] = __builtin_amdgcn_mfma_i32_16x16x64_i8(
                  af[mf][sa], bf[nf][sb], acc[gi][mf][nf], 0, 0, 0);
        }
    }

    // epilogue: out = sum_g acc_g * 2^(Ea+Eb-80+8g), exact pow2 scales
#pragma unroll
    for (int mf = 0; mf < 4; ++mf)
#pragma unroll
      for (int nf = 0; nf < 2; ++nf)
#pragma unroll
        for (int r = 0; r < 4; ++r) {
          const int row = m0 + (qm << 6) + (mf << 4) + dr[r];
          const int col = n0 + (qn << 5) + (nf << 4) + dc[r];
          const int e0 = Ea[row] + Eb[col] - 80;
          double s = 0.0;
#pragma unroll
          for (int g = 8; g >= 3; --g) {
            const long long bits = ((long long)(e0 + 8 * g + 1023)) << 52;
            s += (double)acc[g - 3][mf][nf][r] * __longlong_as_double(bits);
          }
          C[(size_t)row * HDIM + col] = s;
        }
  } else {
    // ---------- fp64 VALU fallback (r9-verified): 128m x 64n, 8x4 micro ----------
    double (*As)[130] = (double(*)[130])smem;                  // [16][130]
    double (*Bs)[66]  = (double(*)[66])(smem + 16640);         // [16][66]
    const int tn = tid & 15;
    const int tm = tid >> 4;
    double acc[8][4] = {};
    for (int kt = 0; kt < 49; ++kt) {
      __syncthreads();
#pragma unroll
      for (int s = 0; s < 2; ++s) {
        const int idx = tid + (s << 8);
        const int row = idx >> 2;
        const int kc  = (idx & 3) << 2;
        const float4 a = *(const float4*)(A + (size_t)(m0 + row) * FDIM + kt * 16 + kc);
        As[kc + 0][row] = (double)a.x; As[kc + 1][row] = (double)a.y;
        As[kc + 2][row] = (double)a.z; As[kc + 3][row] = (double)a.w;
      }
      {
        const int row = tid >> 2;
        const int kc  = (tid & 3) << 2;
        const float4 b = *(const float4*)(B + (size_t)(n0 + row) * FDIM + kt * 16 + kc);
        Bs[kc + 0][row] = (double)b.x; Bs[kc + 1][row] = (double)b.y;
        Bs[kc + 2][row] = (double)b.z; Bs[kc + 3][row] = (double)b.w;
      }
      __syncthreads();
#pragma unroll
      for (int kk = 0; kk < 16; ++kk) {
        double av[8], bv[4];
        *(double2*)&av[0] = *(const double2*)&As[kk][(tm << 3) + 0];
        *(double2*)&av[2] = *(const double2*)&As[kk][(tm << 3) + 2];
        *(double2*)&av[4] = *(const double2*)&As[kk][(tm << 3) + 4];
        *(double2*)&av[6] = *(const double2*)&As[kk][(tm << 3) + 6];
        *(double2*)&bv[0] = *(const double2*)&Bs[kk][(tn << 2) + 0];
        *(double2*)&bv[2] = *(const double2*)&Bs[kk][(tn << 2) + 2];
#pragma unroll
        for (int i = 0; i < 8; ++i)
#pragma unroll
          for (int j2 = 0; j2 < 4; ++j2) acc[i][j2] += av[i] * bv[j2];
      }
    }
#pragma unroll
    for (int i = 0; i < 8; ++i) {
      double* crow = C + (size_t)(m0 + (tm << 3) + i) * HDIM + n0 + (tn << 2);
      *(double2*)(crow)     = make_double2(acc[i][0], acc[i][1]);
      *(double2*)(crow + 2) = make_double2(acc[i][2], acc[i][3]);
    }
  }
}

// ---------------- transpose w_rec [512][512] -> wrt [k][h] ----------------
__global__ __launch_bounds__(256) void transpose_kernel(const float* __restrict__ src,
                                                        float* __restrict__ dst) {
  __shared__ float tile[32][33];
  const int bx = blockIdx.x & 15, by = blockIdx.x >> 4;
  const int tx = threadIdx.x & 31, ty = threadIdx.x >> 5;
  const int x = (bx << 5) + tx;
#pragma unroll
  for (int s = 0; s < 32; s += 8)
    tile[ty + s][tx] = src[(size_t)((by << 5) + ty + s) * HDIM + x];
  __syncthreads();
  const int xo = (by << 5) + tx;
#pragma unroll
  for (int s = 0; s < 32; s += 8)
    dst[(size_t)((bx << 5) + ty + s) * HDIM + xo] = tile[tx][ty + s];
}

// ---------------- w_out [10][512] -> wot [k][16] ----------------
__global__ __launch_bounds__(256) void wot_kernel(const float* __restrict__ w_out,
                                                  float* __restrict__ wot) {
  const int k = (blockIdx.x << 8) + threadIdx.x;
#pragma unroll
  for (int o = 0; o < ODIM; ++o) wot[(k << 4) + o] = w_out[(size_t)o * HDIM + k];
}

// ---------------- K2: persistent LIF+LI, one block per batch element ----------
__global__ __launch_bounds__(256) void lif_kernel(const double* __restrict__ cin,
                                                  const float* __restrict__ wrt,
                                                  const float* __restrict__ wot,
                                                  float* __restrict__ out) {
  const int b = blockIdx.x;
  const int tid = threadIdx.x;
  const int h0 = tid, h1 = tid + 256;

  __shared__ unsigned long long masks[8];
  __shared__ int offs[9];
  __shared__ __align__(8) unsigned short list[528];
  __shared__ double ypart[256];

  if (tid == 0) offs[8] = 0;
  __syncthreads();

  double v0 = 0.0, v1 = 0.0, i0 = 0.0, i1 = 0.0;
  double lv = 0.0, li = 0.0;

  const double* cinb = cin + (size_t)b * HDIM;
  float* outb = out + (size_t)b * ODIM;

  for (int t = 0; t < TT; ++t) {
    const double vd0 = v0 + DTM * ((0.0 - v0) + i0);
    const double vd1 = v1 + DTM * ((0.0 - v1) + i1);
    const bool s0 = (vd0 - 1.0) > 0.0;
    const bool s1 = (vd1 - 1.0) > 0.0;
    v0 = s0 ? 0.0 : vd0;
    v1 = s1 ? 0.0 : vd1;
    i0 = i0 - DTS * i0;
    i1 = i1 - DTS * i1;

    const double c0 = cinb[(size_t)t * NSTATE + h0];
    const double c1 = cinb[(size_t)t * NSTATE + h1];

    {
      const int nf = offs[8];
      const int nfp = (nf + 3) & ~3;
      if (nfp > 0) {
        float A0[4], A1[4], B0[4] = {}, B1[4] = {};
#define LOADG(base, X0, X1)                                                   \
        do {                                                                  \
          const unsigned long long le = *(const unsigned long long*)&list[base]; \
          const int k0 = (int)(le & 0xffffu), k1 = (int)((le >> 16) & 0xffffu); \
          const int k2 = (int)((le >> 32) & 0xffffu), k3 = (int)(le >> 48);   \
          X0[0] = wrt[(k0 << 9) + h0]; X1[0] = wrt[(k0 << 9) + h1];           \
          X0[1] = wrt[(k1 << 9) + h0]; X1[1] = wrt[(k1 << 9) + h1];           \
          X0[2] = wrt[(k2 << 9) + h0]; X1[2] = wrt[(k2 << 9) + h1];           \
          X0[3] = wrt[(k3 << 9) + h0]; X1[3] = wrt[(k3 << 9) + h1];           \
        } while (0)
        LOADG(0, A0, A1);
        for (int g = 0; g < nfp; g += 4) {
          if (g + 4 < nfp) LOADG(g + 4, B0, B1);
          i0 += (double)A0[0]; i1 += (double)A1[0];
          i0 += (double)A0[1]; i1 += (double)A1[1];
          i0 += (double)A0[2]; i1 += (double)A1[2];
          i0 += (double)A0[3]; i1 += (double)A1[3];
#pragma unroll
          for (int j = 0; j < 4; ++j) { A0[j] = B0[j]; A1[j] = B1[j]; }
        }
#undef LOADG
      }
    }
    i0 += c0;
    i1 += c1;

    __syncthreads();  // B1

    {
      const unsigned long long m0 = __ballot(s0);
      const unsigned long long m1 = __ballot(s1);
      const int w = tid >> 6;
      if ((tid & 63) == 0) { masks[w] = m0; masks[4 + w] = m1; }
    }
    __syncthreads();  // B2
    if (tid == 0) {
      int rr = 0;
#pragma unroll
      for (int q = 0; q < 8; ++q) { offs[q] = rr; rr += __popcll(masks[q]); }
      offs[8] = rr;
    }
    __syncthreads();  // B3
    if (tid < 8) {
      unsigned long long m = masks[tid];
      int o = offs[tid];
      const int base = tid << 6;
      while (m) {
        list[o++] = (unsigned short)(base + __builtin_ctzll(m));
        m &= m - 1;
      }
    }
    if (tid < 4) list[offs[8] + tid] = 512;
    __syncthreads();  // B4

    {
      const int o = tid & 15, q = tid >> 4;
      const int nfc = offs[8];
      double yp = 0.0;
      int kk = q;
      if (kk < nfc) {
        float f = wot[((int)list[kk] << 4) + o];
        for (kk += 16; kk < nfc; kk += 16) {
          const float fn = wot[((int)list[kk] << 4) + o];
          yp += (double)f;
          f = fn;
        }
        yp += (double)f;
      }
      ypart[(o << 4) + q] = yp;
    }
    __syncthreads();  // B5
    if (tid < ODIM) {
      double y = 0.0;
      const double* yr = &ypart[tid << 4];
#pragma unroll
      for (int q = 0; q < 16; ++q) y += yr[q];
      const double lvn = lv + DTM * ((0.0 - lv) + li);
      li = (li - DTS * li) + y;
      lv = lvn;
      outb[(size_t)t * (BATCH * ODIM) + tid] = (float)lvn;
    }
  }
}

extern "C" void kernel_launch(void* const* d_in, const int* in_sizes, int n_in,
                              void* d_out, int out_size, void* d_ws, size_t ws_size,
                              hipStream_t stream) {
  const float* x     = (const float*)d_in[0];   // [100,512,784]
  const float* w_in  = (const float*)d_in[1];   // [512,784]
  const float* w_rec = (const float*)d_in[2];   // [512,512]
  const float* w_out = (const float*)d_in[3];   // [10,512]
  float* out = (float*)d_out;                   // [100,512,10] fp32

  const size_t CIN = (size_t)TT * BATCH * HDIM;         // 26,214,400 doubles
  double* cin = (double*)d_ws;
  float* wrt  = (float*)(cin + CIN);                    // [513][512], row 512 zeros
  float* wot  = wrt + 513 * 512;                        // [513][16]
  int*   flags = (int*)(wot + 513 * 16);                // 4 ints
  signed char* xslc = (signed char*)(flags + 4);        // [5][51200][832]
  signed char* wslc = xslc + 5ull * 51200 * KPAD;       // [5][512][832]
  int* Ea = (int*)(wslc + 5ull * 512 * KPAD);           // [51200]
  int* Eb = Ea + 51200;                                 // [512]

  const size_t zero_bytes = (513ull * 512 + 513ull * 16) * sizeof(float);
  const size_t need_min = CIN * sizeof(double) + zero_bytes + 16;
  const size_t need_i8  = need_min + 5ull * 51200 * KPAD + 5ull * 512 * KPAD
                        + (51200ull + 512) * sizeof(int);
  if (ws_size < need_min) {
    hipMemsetAsync(d_out, 0x7F, (size_t)out_size * sizeof(float), stream);
    return;
  }
  const bool use_i8 = (ws_size >= need_i8);

  hipMemsetAsync(wrt, 0, zero_bytes, stream);
  if (use_i8) {
    probe_kernel<<<1, 64, 0, stream>>>(flags);
    slice_kernel<<<12800, 256, 0, stream>>>(x, 51200, xslc, Ea);
    slice_kernel<<<128, 256, 0, stream>>>(w_in, 512, wslc, Eb);
  } else {
    hipMemsetAsync(flags, 0xFF, 4, stream);   // flag = -1 -> fp64 fallback path
  }
  transpose_kernel<<<256, 256, 0, stream>>>(w_rec, wrt);
  wot_kernel<<<2, 256, 0, stream>>>(w_out, wot);
  gemm_in_kernel<<<3200, 256, 0, stream>>>(x, w_in, xslc, wslc, Ea, Eb,
                                           cin, flags);
  lif_kernel<<<BATCH, 256, 0, stream>>>(cin, wrt, wot, out);
}